// Round 1
// baseline (429.114 us; speedup 1.0000x reference)
//
#include <hip/hip_runtime.h>

// Problem constants
constexpr int NB   = 2;
constexpr int CIN  = 128;
constexpr int TT   = 8;
constexpr int HH   = 56;
constexpr int WW   = 56;
constexpr int S    = TT * HH * WW;      // 25088 positions per batch
constexpr int DK   = 16;
constexpr int DV   = 128;
constexpr int TAPS = 147;               // 3*7*7
constexpr float EPSf = 1e-6f;

// ---------------------------------------------------------------------------
// Kernel 1: projection + q-norm + v sumsq.  One thread per (b, p) position.
// x[128] held in registers; W_proj rows are wave-uniform -> scalar loads.
// ---------------------------------------------------------------------------
__global__ __launch_bounds__(64) void k_proj(
    const float* __restrict__ x, const float* __restrict__ Wp,
    float* __restrict__ qn, float* __restrict__ vraw, float* __restrict__ invv)
{
    int gid = blockIdx.x * 64 + threadIdx.x;      // < NB*S = 50176
    int b = gid / S, p = gid - b * S;
    const float* xb = x + (size_t)b * CIN * S + p;

    float xr[CIN];
#pragma unroll
    for (int c = 0; c < CIN; ++c) xr[c] = xb[(size_t)c * S];

    // q channels 0..15, normalized over the 16-channel group
    float qv[DK];
    float ssq = 0.f;
#pragma unroll 1
    for (int o = 0; o < DK; ++o) {
        const float* w = Wp + (size_t)o * CIN;
        float a = 0.f;
#pragma unroll
        for (int c = 0; c < CIN; ++c) a = fmaf(w[c], xr[c], a);
        qv[o] = a;
        ssq += a * a;
    }
    float qs = 1.0f / sqrtf(ssq + EPSf);
#pragma unroll
    for (int o = 0; o < DK; ++o)
        qn[((size_t)b * DK + o) * S + p] = qv[o] * qs;

    // v channels 16..143: write raw, track sum of squares
    float ssv = 0.f;
#pragma unroll 1
    for (int o = 0; o < DV; ++o) {
        const float* w = Wp + (size_t)(DK + o) * CIN;
        float a = 0.f;
#pragma unroll
        for (int c = 0; c < CIN; ++c) a = fmaf(w[c], xr[c], a);
        ssv += a * a;
        vraw[((size_t)b * DV + o) * S + p] = a;
    }
    invv[gid] = 1.0f / sqrtf(ssv + EPSf);
}

// ---------------------------------------------------------------------------
// Kernel 2: normalize v in place (float4).
// ---------------------------------------------------------------------------
__global__ __launch_bounds__(256) void k_vscale(
    float* __restrict__ v, const float* __restrict__ invv)
{
    size_t i4 = (size_t)blockIdx.x * 256 + threadIdx.x; // over NB*DV*S/4
    size_t e = i4 * 4;
    int b = (int)(e / ((size_t)DV * S));
    int p = (int)(e % S);
    float4 vv = *reinterpret_cast<const float4*>(v + e);
    float4 g  = *reinterpret_cast<const float4*>(invv + (size_t)b * S + p);
    vv.x *= g.x; vv.y *= g.y; vv.z *= g.z; vv.w *= g.w;
    *reinterpret_cast<float4*>(v + e) = vv;
}

// ---------------------------------------------------------------------------
// Kernel 3: Weff[b][tap][p] = sum_k q[b,k,p] * W_H2[k,tap]
// One thread per (b,p); q[16] in registers; W_H2 wave-uniform scalar loads.
// ---------------------------------------------------------------------------
__global__ __launch_bounds__(64) void k_weff(
    const float* __restrict__ qn, const float* __restrict__ wh2,
    float* __restrict__ weff)
{
    int gid = blockIdx.x * 64 + threadIdx.x;     // < NB*S
    int b = gid / S, p = gid - b * S;
    float q[DK];
#pragma unroll
    for (int k = 0; k < DK; ++k) q[k] = qn[((size_t)b * DK + k) * S + p];
#pragma unroll 1
    for (int tap = 0; tap < TAPS; ++tap) {
        float a = 0.f;
#pragma unroll
        for (int k = 0; k < DK; ++k) a = fmaf(q[k], wh2[k * TAPS + tap], a);
        weff[((size_t)b * TAPS + tap) * S + p] = a;
    }
}

// ---------------------------------------------------------------------------
// Kernel 4: out[b,c,p] = sum over valid taps Weff[b,p,tap] * v[b,c,p+off]
// Thread = (p, 8-channel group). Weff load amortized over 8 channels.
// ---------------------------------------------------------------------------
__global__ __launch_bounds__(256) void k_out(
    const float* __restrict__ v, const float* __restrict__ weff,
    float* __restrict__ out)
{
    int p  = blockIdx.x * 256 + threadIdx.x;     // 98 blocks * 256 = 25088
    int cg = blockIdx.y;                          // 0..15 -> 8 channels each
    int b  = blockIdx.z;

    int t  = p / (HH * WW);
    int hw = p - t * HH * WW;
    int h  = hw / WW;
    int w  = hw - h * WW;

    int dz0 = max(0, 1 - t), dz1 = min(3, 9 - t);
    int dy0 = max(0, 3 - h), dy1 = min(7, 59 - h);
    int dx0 = max(0, 3 - w), dx1 = min(7, 59 - w);

    const float* vb = v + ((size_t)b * DV + cg * 8) * S + p;
    const float* wb = weff + (size_t)b * TAPS * S + p;

    float acc[8] = {0.f, 0.f, 0.f, 0.f, 0.f, 0.f, 0.f, 0.f};

    for (int dz = dz0; dz < dz1; ++dz) {
        for (int dy = dy0; dy < dy1; ++dy) {
            int rowoff = (dz - 1) * HH * WW + (dy - 3) * WW - 3;
            const float* wrow = wb + (size_t)((dz * 7 + dy) * 7) * S;
            for (int dx = dx0; dx < dx1; ++dx) {
                float wv = wrow[(size_t)dx * S];
                ptrdiff_t off = rowoff + dx;
#pragma unroll
                for (int j = 0; j < 8; ++j)
                    acc[j] = fmaf(wv, vb[(ptrdiff_t)j * S + off], acc[j]);
            }
        }
    }
#pragma unroll
    for (int j = 0; j < 8; ++j)
        out[((size_t)b * DV + cg * 8 + j) * S + p] = acc[j];
}

// ---------------------------------------------------------------------------
extern "C" void kernel_launch(void* const* d_in, const int* in_sizes, int n_in,
                              void* d_out, int out_size, void* d_ws, size_t ws_size,
                              hipStream_t stream)
{
    const float* x   = (const float*)d_in[0];   // (2,128,8,56,56)
    const float* Wp  = (const float*)d_in[1];   // (144,128)
    const float* wh2 = (const float*)d_in[2];   // (16,1,3,7,7) -> [k][147]
    float* out = (float*)d_out;                 // (2,128,8,56,56)

    float* ws   = (float*)d_ws;
    float* qn   = ws;                               // NB*DK*S   =   802,816
    float* vr   = qn   + (size_t)NB * DK * S;       // NB*DV*S   = 6,422,528
    float* invv = vr   + (size_t)NB * DV * S;       // NB*S      =    50,176
    float* weff = invv + (size_t)NB * S;            // NB*TAPS*S = 7,375,872

    k_proj  <<<dim3(NB * S / 64), dim3(64),  0, stream>>>(x, Wp, qn, vr, invv);
    k_vscale<<<dim3(NB * DV * S / 4 / 256), dim3(256), 0, stream>>>(vr, invv);
    k_weff  <<<dim3(NB * S / 64), dim3(64),  0, stream>>>(qn, wh2, weff);
    k_out   <<<dim3(S / 256, DV / 8, NB), dim3(256), 0, stream>>>(vr, weff, out);
}